// Round 5
// baseline (266.860 us; speedup 1.0000x reference)
//
#include <hip/hip_runtime.h>
#include <hip/hip_bf16.h>

#define DM   512
#define HEADS 8
#define DKH  64
#define BATCH 2
#define SEQ  4096

typedef float  f32x4  __attribute__((ext_vector_type(4)));
typedef float  f32x16 __attribute__((ext_vector_type(16)));
typedef __bf16 bf16x8 __attribute__((ext_vector_type(8)));
typedef __bf16 bf16x2 __attribute__((ext_vector_type(2)));

static __device__ __forceinline__ f32x4 mfma16(bf16x8 a, bf16x8 b, f32x4 c) {
    return __builtin_amdgcn_mfma_f32_16x16x32_bf16(a, b, c, 0, 0, 0);
}
static __device__ __forceinline__ f32x16 mfma32(bf16x8 a, bf16x8 b, f32x16 c) {
    return __builtin_amdgcn_mfma_f32_32x32x16_bf16(a, b, c, 0, 0, 0);
}

#define GLD16(gp, lp) __builtin_amdgcn_global_load_lds( \
    (const __attribute__((address_space(1))) void*)(gp), \
    (__attribute__((address_space(3))) void*)(lp), 16, 0, 0)

#define WAITVM(n) asm volatile("s_waitcnt vmcnt(" #n ")" ::: "memory")

static __device__ __forceinline__ void barrier_sync() {
    __builtin_amdgcn_sched_barrier(0);
    asm volatile("" ::: "memory");
    __builtin_amdgcn_s_barrier();
    asm volatile("" ::: "memory");
    __builtin_amdgcn_sched_barrier(0);
}

// ---------------------------------------------------------------------------
// fp32 -> bf16 elementwise, 3 tensors (blockIdx.y selects), 8 elems/thread
// ---------------------------------------------------------------------------
struct Cvt3 { const float* s[3]; __bf16* d[3]; };

__global__ __launch_bounds__(256) void convert_x3(Cvt3 a) {
    const float* s = a.s[blockIdx.y];
    __bf16* d = a.d[blockIdx.y];
    const size_t i = ((size_t)blockIdx.x * 256 + threadIdx.x) * 8;
    f32x4 f0 = *(const f32x4*)&s[i];
    f32x4 f1 = *(const f32x4*)&s[i + 4];
    bf16x8 v;
    v[0] = (__bf16)f0[0]; v[1] = (__bf16)f0[1]; v[2] = (__bf16)f0[2]; v[3] = (__bf16)f0[3];
    v[4] = (__bf16)f1[0]; v[5] = (__bf16)f1[1]; v[6] = (__bf16)f1[2]; v[7] = (__bf16)f1[3];
    *(bf16x8*)&d[i] = v;
}

// ---------------------------------------------------------------------------
// All four W [k][n] fp32 -> Wt [n][k] bf16 in one launch (z = weight index)
// ---------------------------------------------------------------------------
struct WtAll { const float* W[4]; __bf16* Wt[4]; };

__global__ __launch_bounds__(256) void wt_convert_all(WtAll a) {
    const float* W = a.W[blockIdx.z];
    __bf16* Wt = a.Wt[blockIdx.z];
    __shared__ float tile[32][33];
    const int tx = threadIdx.x & 31, ty = threadIdx.x >> 5;
    const int nb = blockIdx.x * 32, kb = blockIdx.y * 32;
#pragma unroll
    for (int i = 0; i < 4; ++i)
        tile[ty + 8 * i][tx] = W[(size_t)(kb + ty + 8 * i) * DM + nb + tx];
    __syncthreads();
#pragma unroll
    for (int i = 0; i < 4; ++i)
        Wt[(size_t)(nb + ty + 8 * i) * DM + kb + tx] = (__bf16)tile[tx][ty + 8 * i];
}

// ---------------------------------------------------------------------------
// 128xBN bf16 GEMM, counted-vmcnt 2-deep pipeline, XOR-swizzled LDS.
// Out[m][n] = (A[m][k] * W[k][n] + bias[n]) * ascale
// ---------------------------------------------------------------------------
struct Ptr3 { const __bf16* A; const __bf16* Bt; const float* bias; void* Out; float ascale; };
struct GemmArgs { Ptr3 p[3]; };

template <bool OUT_BF16, int BN>
__global__ __launch_bounds__(256) void gemm_tile(GemmArgs args) {
    constexpr int BGLD = BN / 32;           // B GLD16 issues per wave per tile
    constexpr int NJ   = BN / 32;           // B fragments per wave
    constexpr int NT   = DM / 64;           // 8 K-tiles
    __shared__ __bf16 Al[2][128][64];
    __shared__ __bf16 Bl[2][BN][64];
    const Ptr3 P = args.p[blockIdx.z];
    const int tid = threadIdx.x;
    const int lane = tid & 63, wid = tid >> 6;
    const int lq = lane & 15, hi = lane >> 4;
    const int m0 = blockIdx.x * 128, n0 = blockIdx.y * BN;
    const int wm = (wid >> 1) * 64, wn = (wid & 1) * (BN / 2);

    // --- staging pointers (pre-swizzled global source, linear LDS dest) ---
    const int lrow = lane >> 3, lslot = lane & 7;
    const __bf16* gaP[4];
#pragma unroll
    for (int i = 0; i < 4; ++i) {
        const int r = wid * 32 + i * 8 + lrow;
        const int s = lslot ^ ((r ^ (r >> 3)) & 7);
        gaP[i] = P.A + (size_t)(m0 + r) * DM + s * 8;
    }
    const __bf16* gbP[BGLD];
#pragma unroll
    for (int i = 0; i < BGLD; ++i) {
        const int r = wid * (BN / 4) + i * 8 + lrow;
        const int s = lslot ^ ((r ^ (r >> 3)) & 7);
        gbP[i] = P.Bt + (size_t)(n0 + r) * DM + s * 8;
    }
    auto stage = [&](int kt, int buf) {
        const int k0 = kt * 64;
#pragma unroll
        for (int i = 0; i < 4; ++i)
            GLD16(gaP[i] + k0, &Al[buf][wid * 32 + i * 8][0]);
#pragma unroll
        for (int i = 0; i < BGLD; ++i)
            GLD16(gbP[i] + k0, &Bl[buf][wid * (BN / 4) + i * 8][0]);
    };

    // --- read-side addresses (row base + swizzle) ---
    int baseA[4], swA[4];
#pragma unroll
    for (int i = 0; i < 4; ++i) {
        const int r = wm + i * 16 + lq;
        baseA[i] = r * 128;
        swA[i] = (((r ^ (r >> 3)) & 7) << 4);
    }
    int baseB[NJ], swB[NJ];
#pragma unroll
    for (int j = 0; j < NJ; ++j) {
        const int r = wn + j * 16 + lq;
        baseB[j] = r * 128;
        swB[j] = (((r ^ (r >> 3)) & 7) << 4);
    }

    f32x4 acc[4][NJ] = {};

    stage(0, 0);
    stage(1, 1);
    for (int kt = 0; kt < NT; ++kt) {
        const int cur = kt & 1;
        if (kt + 1 < NT) {
            if (BN == 128) { WAITVM(8); } else { WAITVM(6); }
        } else { WAITVM(0); }
        barrier_sync();
        const char* Ab = (const char*)&Al[cur][0][0];
        const char* Bb = (const char*)&Bl[cur][0][0];
        __builtin_amdgcn_s_setprio(1);
#pragma unroll
        for (int ks = 0; ks < 2; ++ks) {
            const int off = ks * 64 + hi * 16;
            bf16x8 af[4], bfv[NJ];
#pragma unroll
            for (int i = 0; i < 4; ++i)
                af[i] = *(const bf16x8*)(Ab + baseA[i] + (off ^ swA[i]));
#pragma unroll
            for (int j = 0; j < NJ; ++j)
                bfv[j] = *(const bf16x8*)(Bb + baseB[j] + (off ^ swB[j]));
#pragma unroll
            for (int i = 0; i < 4; ++i)
#pragma unroll
                for (int j = 0; j < NJ; ++j)
                    acc[i][j] = mfma16(af[i], bfv[j], acc[i][j]);
        }
        __builtin_amdgcn_s_setprio(0);
        if (kt + 2 < NT) {
            barrier_sync();
            stage(kt + 2, cur);
        }
    }

    const float* bias = P.bias;
    const float asc = P.ascale;
#pragma unroll
    for (int j = 0; j < NJ; ++j) {
        const int n = n0 + wn + j * 16 + lq;
        const float bv = bias[n];
#pragma unroll
        for (int i = 0; i < 4; ++i) {
#pragma unroll
            for (int r = 0; r < 4; ++r) {
                const int m = m0 + wm + i * 16 + hi * 4 + r;
                const float v = (acc[i][j][r] + bv) * asc;
                if (OUT_BF16) ((__bf16*)P.Out)[(size_t)m * DM + n] = (__bf16)v;
                else          ((float*)P.Out)[(size_t)m * DM + n] = v;
            }
        }
    }
}

// ---------------------------------------------------------------------------
// Vp [b*S][512] bf16 -> Vt [bh][dk=64][S] bf16  (per-head transpose)
// ---------------------------------------------------------------------------
__global__ __launch_bounds__(256) void v_transpose(const __bf16* __restrict__ Vp,
                                                   __bf16* __restrict__ Vt) {
    __shared__ __bf16 tile[64][72];
    const int tid = threadIdx.x;
    const int tt = blockIdx.x * 64;
    const int bh = blockIdx.y, b = bh >> 3, h = bh & 7;
#pragma unroll
    for (int i = 0; i < 2; ++i) {
        int c = tid + 256 * i, row = c >> 3, cc = c & 7;
        *(bf16x8*)&tile[row][cc * 8] =
            *(const bf16x8*)&Vp[(size_t)(b * SEQ + tt + row) * DM + h * DKH + cc * 8];
    }
    __syncthreads();
#pragma unroll
    for (int i = 0; i < 2; ++i) {
        int c = tid + 256 * i, row = c >> 3, cc = c & 7;
        bf16x8 v;
#pragma unroll
        for (int j = 0; j < 8; ++j) v[j] = tile[cc * 8 + j][row];
        *(bf16x8*)&Vt[(size_t)(bh * DKH + row) * SEQ + tt + cc * 8] = v;
    }
}

// ---------------------------------------------------------------------------
// Flash attention, 32x32x16 MFMA, 4 waves x 32 q = 128 q per block.
// Counted-vmcnt 2-deep K/V pipeline; l accumulated via MFMA with B = ones.
// ---------------------------------------------------------------------------
template <bool SPLIT>
__global__ __launch_bounds__(256, 4) void flash_attn4(const __bf16* __restrict__ Qp,
                                                      const __bf16* __restrict__ Kp,
                                                      const __bf16* __restrict__ Vt,
                                                      __bf16* __restrict__ O0,
                                                      __bf16* __restrict__ O1,
                                                      float* __restrict__ MLM,
                                                      float* __restrict__ MLL) {
    __shared__ __bf16 Kl[2][64][64];   // swizzled: slot ^= (row^(row>>3))&7
    __shared__ __bf16 Vl[2][64][64];
    __shared__ float  Lbuf[4][32];     // per-wave alpha broadcast

    const int tid = threadIdx.x, lane = tid & 63, w = tid >> 6;
    const int c = lane & 31, h = lane >> 5;
    const int bh = blockIdx.y, b = bh >> 3, hd = bh & 7;
    const int qbase = blockIdx.x * 128 + w * 32;
    const int kvoff = SPLIT ? blockIdx.z * (SEQ / 2) : 0;
    const int NT = SPLIT ? (SEQ / 2) / 64 : SEQ / 64;

    bf16x8 qf[4];
#pragma unroll
    for (int t = 0; t < 4; ++t)
        qf[t] = *(const bf16x8*)&Qp[(size_t)(b * SEQ + qbase + c) * DM + hd * DKH + 16 * t + 8 * h];

    const int r0 = w * 16 + (lane >> 3);
    const int r1 = r0 + 8;
    const int s0 = (lane & 7) ^ ((r0 ^ (r0 >> 3)) & 7);
    const int s1 = (lane & 7) ^ ((r1 ^ (r1 >> 3)) & 7);
    const __bf16* kg0 = Kp + (size_t)(b * SEQ + kvoff + r0) * DM + hd * DKH + s0 * 8;
    const __bf16* kg1 = Kp + (size_t)(b * SEQ + kvoff + r1) * DM + hd * DKH + s1 * 8;
    const __bf16* vg0 = Vt + (size_t)(bh * DKH + r0) * SEQ + kvoff + s0 * 8;
    const __bf16* vg1 = Vt + (size_t)(bh * DKH + r1) * SEQ + kvoff + s1 * 8;

    const int swz0 = (c ^ (c >> 3)) & 7;
    const int swz1 = ((32 + c) ^ ((32 + c) >> 3)) & 7;
    const int rowb0 = c * 128, rowb1 = (32 + c) * 128;
    const char* kb = (const char*)&Kl[0][0][0];
    const char* vb = (const char*)&Vl[0][0][0];

    auto stage = [&](int t, int buf) {
        const size_t ko = (size_t)t * 64 * DM, vo = (size_t)t * 64;
        GLD16(kg0 + ko, &Kl[buf][w * 16][0]);
        GLD16(kg1 + ko, &Kl[buf][w * 16 + 8][0]);
        GLD16(vg0 + vo, &Vl[buf][w * 16][0]);
        GLD16(vg1 + vo, &Vl[buf][w * 16 + 8][0]);
    };

    bf16x8 vone;
#pragma unroll
    for (int j = 0; j < 8; ++j) vone[j] = (__bf16)1.0f;

    f32x16 acc0 = {}, acc1 = {}, lacc = {};
    float m_run = -__builtin_inff();

    stage(0, 0);
    stage(1, 1);

    for (int t = 0; t < NT; ++t) {
        const int cur = t & 1;
        if (t + 1 < NT) { WAITVM(4); } else { WAITVM(0); }
        barrier_sync();
        const char* kc = kb + cur * 8192;
        const char* vc = vb + cur * 8192;

        // ---- QK^T
        f32x16 sa = {}, sb = {};
        __builtin_amdgcn_s_setprio(1);
#pragma unroll
        for (int tt = 0; tt < 4; ++tt) {
            bf16x8 kf0 = *(const bf16x8*)(kc + rowb0 + (((2 * tt + h) ^ swz0) << 4));
            sa = mfma32(kf0, qf[tt], sa);
            bf16x8 kf1 = *(const bf16x8*)(kc + rowb1 + (((2 * tt + h) ^ swz1) << 4));
            sb = mfma32(kf1, qf[tt], sb);
        }
        __builtin_amdgcn_s_setprio(0);

        // ---- online softmax (exp2 domain), defer-max THR=8
        float mx = fmaxf(sa[0], sa[1]);
#pragma unroll
        for (int r = 2; r < 16; r += 2) mx = fmaxf(mx, fmaxf(sa[r], sa[r + 1]));
#pragma unroll
        for (int r = 0; r < 16; r += 2) mx = fmaxf(mx, fmaxf(sb[r], sb[r + 1]));
        mx = fmaxf(mx, __shfl_xor(mx, 32));
        if (!__all(mx <= m_run + 8.f)) {
            const float mnew = fmaxf(m_run, mx);
            const float al = __builtin_amdgcn_exp2f(m_run - mnew);
            m_run = mnew;
            if (lane < 32) Lbuf[w][lane] = al;
#pragma unroll
            for (int r = 0; r < 16; ++r) {
                const float a2 = Lbuf[w][(r & 3) + 8 * (r >> 2) + 4 * h];
                acc0[r] *= a2; acc1[r] *= a2; lacc[r] *= a2;
            }
        }

        // ---- exp2 + pack to bf16 pairs (fused, low VGPR peak)
        int ua[4][2], ub[4][2];
#pragma unroll
        for (int q4 = 0; q4 < 4; ++q4) {
            float p0 = __builtin_amdgcn_exp2f(sa[4 * q4 + 0] - m_run);
            float p1 = __builtin_amdgcn_exp2f(sa[4 * q4 + 1] - m_run);
            float p2 = __builtin_amdgcn_exp2f(sa[4 * q4 + 2] - m_run);
            float p3 = __builtin_amdgcn_exp2f(sa[4 * q4 + 3] - m_run);
            bf16x2 t0; t0[0] = (__bf16)p0; t0[1] = (__bf16)p1;
            bf16x2 t1; t1[0] = (__bf16)p2; t1[1] = (__bf16)p3;
            ua[q4][0] = __builtin_bit_cast(int, t0);
            ua[q4][1] = __builtin_bit_cast(int, t1);
        }
#pragma unroll
        for (int q4 = 0; q4 < 4; ++q4) {
            float p0 = __builtin_amdgcn_exp2f(sb[4 * q4 + 0] - m_run);
            float p1 = __builtin_amdgcn_exp2f(sb[4 * q4 + 1] - m_run);
            float p2 = __builtin_amdgcn_exp2f(sb[4 * q4 + 2] - m_run);
            float p3 = __builtin_amdgcn_exp2f(sb[4 * q4 + 3] - m_run);
            bf16x2 t0; t0[0] = (__bf16)p0; t0[1] = (__bf16)p1;
            bf16x2 t1; t1[0] = (__bf16)p2; t1[1] = (__bf16)p3;
            ub[q4][0] = __builtin_bit_cast(int, t0);
            ub[q4][1] = __builtin_bit_cast(int, t1);
        }

        // ---- PV (+ l accumulation via MFMA with B = ones)
#pragma unroll
        for (int tg = 0; tg < 4; ++tg) {
            int x0, y0, x1, y1;
            if (tg < 2) {
                x0 = ua[2 * tg][0]; y0 = ua[2 * tg + 1][0];
                x1 = ua[2 * tg][1]; y1 = ua[2 * tg + 1][1];
            } else {
                x0 = ub[2 * (tg - 2)][0]; y0 = ub[2 * (tg - 2) + 1][0];
                x1 = ub[2 * (tg - 2)][1]; y1 = ub[2 * (tg - 2) + 1][1];
            }
            asm("v_permlane32_swap_b32 %0, %1" : "+v"(x0), "+v"(y0));
            asm("v_permlane32_swap_b32 %0, %1" : "+v"(x1), "+v"(y1));
            union { int i4[4]; bf16x8 v; } pf;
            pf.i4[0] = x0; pf.i4[1] = x1; pf.i4[2] = y0; pf.i4[3] = y1;
            bf16x8 vf0 = *(const bf16x8*)(vc + rowb0 + (((2 * tg + h) ^ swz0) << 4));
            bf16x8 vf1 = *(const bf16x8*)(vc + rowb1 + (((2 * tg + h) ^ swz1) << 4));
            __builtin_amdgcn_s_setprio(1);
            acc0 = mfma32(pf.v, vf0, acc0);
            acc1 = mfma32(pf.v, vf1, acc1);
            lacc = mfma32(pf.v, vone, lacc);
            __builtin_amdgcn_s_setprio(0);
        }

        if (t + 2 < NT) {
            barrier_sync();
            stage(t + 2, cur);
        }
    }

    if (SPLIT) {
        __bf16* pp = blockIdx.z ? O1 : O0;
#pragma unroll
        for (int r = 0; r < 16; ++r) {
            const int qr = (r & 3) + 8 * (r >> 2) + 4 * h;
            const size_t off = (size_t)(b * SEQ + qbase + qr) * DM + hd * DKH;
            pp[off + c]      = (__bf16)acc0[r];
            pp[off + 32 + c] = (__bf16)acc1[r];
        }
        const int zo = blockIdx.z * 16 + bh;
        if (h == 0) MLM[(size_t)zo * SEQ + qbase + c] = m_run;
        if (c == 0) {
#pragma unroll
            for (int r = 0; r < 16; ++r) {
                const int qr = (r & 3) + 8 * (r >> 2) + 4 * h;
                MLL[(size_t)zo * SEQ + qbase + qr] = lacc[r];
            }
        }
    } else {
        __bf16* outp = O0 + (size_t)(b * SEQ + qbase) * DM + hd * DKH;
#pragma unroll
        for (int r = 0; r < 16; ++r) {
            const int qr = (r & 3) + 8 * (r >> 2) + 4 * h;
            const float li = 1.f / lacc[r];
            outp[(size_t)qr * DM + c]      = (__bf16)(acc0[r] * li);
            outp[(size_t)qr * DM + 32 + c] = (__bf16)(acc1[r] * li);
        }
    }
}

// ---------------------------------------------------------------------------
// Combine the two kv-half partials:  Ctx = (P0*e0 + P1*e1) / (l0*e0 + l1*e1)
// ---------------------------------------------------------------------------
__global__ __launch_bounds__(256) void combine(const __bf16* __restrict__ P0,
                                               const __bf16* __restrict__ P1,
                                               const float* __restrict__ MLM,
                                               const float* __restrict__ MLL,
                                               __bf16* __restrict__ Ctx) {
    const int row = blockIdx.x;             // b*SEQ + q
    const int b = row >> 12, q = row & (SEQ - 1);
    const int col = threadIdx.x * 2;
    const int head = col >> 6;
    const int bh = b * HEADS + head;
    const float m0 = MLM[(size_t)bh * SEQ + q];
    const float m1 = MLM[(size_t)(16 + bh) * SEQ + q];
    const float l0 = MLL[(size_t)bh * SEQ + q];
    const float l1 = MLL[(size_t)(16 + bh) * SEQ + q];
    const float m = fmaxf(m0, m1);
    const float e0 = __builtin_amdgcn_exp2f(m0 - m);
    const float e1 = __builtin_amdgcn_exp2f(m1 - m);
    const float inv = 1.f / (l0 * e0 + l1 * e1);
    const float f0 = e0 * inv, f1 = e1 * inv;
    const size_t idx = (size_t)row * DM + col;
    bf16x2 a = *(const bf16x2*)&P0[idx];
    bf16x2 bb = *(const bf16x2*)&P1[idx];
    bf16x2 o;
    o[0] = (__bf16)((float)a[0] * f0 + (float)bb[0] * f1);
    o[1] = (__bf16)((float)a[1] * f0 + (float)bb[1] * f1);
    *(bf16x2*)&Ctx[idx] = o;
}

// ---------------------------------------------------------------------------
extern "C" void kernel_launch(void* const* d_in, const int* in_sizes, int n_in,
                              void* d_out, int out_size, void* d_ws, size_t ws_size,
                              hipStream_t stream) {
    (void)in_sizes; (void)n_in; (void)out_size;
    const float* query = (const float*)d_in[0];
    const float* key_  = (const float*)d_in[1];
    const float* value = (const float*)d_in[2];
    const float* Wq = (const float*)d_in[3];
    const float* bq = (const float*)d_in[4];
    const float* Wk = (const float*)d_in[5];
    const float* bk = (const float*)d_in[6];
    const float* Wv = (const float*)d_in[7];
    const float* bv = (const float*)d_in[8];
    const float* Wo = (const float*)d_in[9];
    const float* bo = (const float*)d_in[10];

    char* ws = (char*)d_ws;
    const size_t WSZ = (size_t)512 * 1024;        // per transposed weight
    const size_t XSZ = (size_t)8 * 1024 * 1024;   // per [8192][512] bf16 buffer
    const float QSC = 0.125f * 1.4426950408889634f;  // 1/sqrt(dk) * log2(e)
    if (ws_size < 4 * WSZ + 7 * XSZ) return;      // 58 MiB needed (proven available)

    __bf16* Wtq = (__bf16*)(ws);
    __bf16* Wtk = (__bf16*)(ws + WSZ);
    __bf16* Wtv = (__bf16*)(ws + 2 * WSZ);
    __bf16* Wto = (__bf16*)(ws + 3 * WSZ);
    char* xb = ws + 4 * WSZ;
    __bf16* Qb = (__bf16*)(xb);
    __bf16* Kb = (__bf16*)(xb + XSZ);
    __bf16* Vb = (__bf16*)(xb + 2 * XSZ);
    __bf16* Qp = (__bf16*)(xb + 3 * XSZ);
    __bf16* Kp = (__bf16*)(xb + 4 * XSZ);
    __bf16* Vp = (__bf16*)(xb + 5 * XSZ);
    __bf16* Vt = (__bf16*)(xb + 6 * XSZ);
    __bf16* Ctx = Vp;                 // Vp dead after v_transpose
    __bf16* P0 = Qb;                  // Qb/Kb/Vb dead after projections
    __bf16* P1 = Kb;
    float* MLM = (float*)Vb;          // 2*16*4096 floats = 512 KB
    float* MLL = MLM + 2 * 16 * SEQ;  // 512 KB

    Cvt3 cv;
    cv.s[0] = query; cv.s[1] = key_; cv.s[2] = value;
    cv.d[0] = Qb; cv.d[1] = Kb; cv.d[2] = Vb;
    convert_x3<<<dim3(2048, 3), 256, 0, stream>>>(cv);

    WtAll wa;
    wa.W[0] = Wq; wa.W[1] = Wk; wa.W[2] = Wv; wa.W[3] = Wo;
    wa.Wt[0] = Wtq; wa.Wt[1] = Wtk; wa.Wt[2] = Wtv; wa.Wt[3] = Wto;
    wt_convert_all<<<dim3(16, 16, 4), 256, 0, stream>>>(wa);

    GemmArgs qa;
    qa.p[0] = {Qb, Wtq, bq, Qp, QSC};
    qa.p[1] = {Kb, Wtk, bk, Kp, 1.0f};
    qa.p[2] = {Vb, Wtv, bv, Vp, 1.0f};
    gemm_tile<true, 128><<<dim3(64, 4, 3), 256, 0, stream>>>(qa);

    v_transpose<<<dim3(SEQ / 64, BATCH * HEADS), 256, 0, stream>>>(Vp, Vt);

    flash_attn4<true><<<dim3(SEQ / 128, BATCH * HEADS, 2), 256, 0, stream>>>(
        Qp, Kp, Vt, P0, P1, MLM, MLL);

    combine<<<dim3(BATCH * SEQ), 256, 0, stream>>>(P0, P1, MLM, MLL, Ctx);

    GemmArgs oa;
    oa.p[0] = {Ctx, Wto, bo, d_out, 1.0f};
    oa.p[1] = oa.p[0]; oa.p[2] = oa.p[0];
    gemm_tile<false, 64><<<dim3(64, 8, 1), 256, 0, stream>>>(oa);
}

// Round 6
// 255.990 us; speedup vs baseline: 1.0425x; 1.0425x over previous
//
#include <hip/hip_runtime.h>
#include <hip/hip_bf16.h>

#define DM   512
#define HEADS 8
#define DKH  64
#define BATCH 2
#define SEQ  4096

typedef float  f32x4  __attribute__((ext_vector_type(4)));
typedef float  f32x16 __attribute__((ext_vector_type(16)));
typedef __bf16 bf16x8 __attribute__((ext_vector_type(8)));
typedef __bf16 bf16x4 __attribute__((ext_vector_type(4)));
typedef __bf16 bf16x2 __attribute__((ext_vector_type(2)));

static __device__ __forceinline__ f32x4 mfma16(bf16x8 a, bf16x8 b, f32x4 c) {
    return __builtin_amdgcn_mfma_f32_16x16x32_bf16(a, b, c, 0, 0, 0);
}
static __device__ __forceinline__ f32x16 mfma32(bf16x8 a, bf16x8 b, f32x16 c) {
    return __builtin_amdgcn_mfma_f32_32x32x16_bf16(a, b, c, 0, 0, 0);
}

#define GLD16(gp, lp) __builtin_amdgcn_global_load_lds( \
    (const __attribute__((address_space(1))) void*)(gp), \
    (__attribute__((address_space(3))) void*)(lp), 16, 0, 0)

#define WAITVM(n) asm volatile("s_waitcnt vmcnt(" #n ")" ::: "memory")

static __device__ __forceinline__ void barrier_sync() {
    __builtin_amdgcn_sched_barrier(0);
    asm volatile("" ::: "memory");
    __builtin_amdgcn_s_barrier();
    asm volatile("" ::: "memory");
    __builtin_amdgcn_sched_barrier(0);
}

// ---------------------------------------------------------------------------
// fp32 -> bf16 elementwise, 3 tensors (blockIdx.y selects), 8 elems/thread
// ---------------------------------------------------------------------------
struct Cvt3 { const float* s[3]; __bf16* d[3]; };

__global__ __launch_bounds__(256) void convert_x3(Cvt3 a) {
    const float* s = a.s[blockIdx.y];
    __bf16* d = a.d[blockIdx.y];
    const size_t i = ((size_t)blockIdx.x * 256 + threadIdx.x) * 8;
    f32x4 f0 = *(const f32x4*)&s[i];
    f32x4 f1 = *(const f32x4*)&s[i + 4];
    bf16x8 v;
    v[0] = (__bf16)f0[0]; v[1] = (__bf16)f0[1]; v[2] = (__bf16)f0[2]; v[3] = (__bf16)f0[3];
    v[4] = (__bf16)f1[0]; v[5] = (__bf16)f1[1]; v[6] = (__bf16)f1[2]; v[7] = (__bf16)f1[3];
    *(bf16x8*)&d[i] = v;
}

// ---------------------------------------------------------------------------
// All four W [k][n] fp32 -> Wt [n][k] bf16 in one launch (z = weight index)
// ---------------------------------------------------------------------------
struct WtAll { const float* W[4]; __bf16* Wt[4]; };

__global__ __launch_bounds__(256) void wt_convert_all(WtAll a) {
    const float* W = a.W[blockIdx.z];
    __bf16* Wt = a.Wt[blockIdx.z];
    __shared__ float tile[32][33];
    const int tx = threadIdx.x & 31, ty = threadIdx.x >> 5;
    const int nb = blockIdx.x * 32, kb = blockIdx.y * 32;
#pragma unroll
    for (int i = 0; i < 4; ++i)
        tile[ty + 8 * i][tx] = W[(size_t)(kb + ty + 8 * i) * DM + nb + tx];
    __syncthreads();
#pragma unroll
    for (int i = 0; i < 4; ++i)
        Wt[(size_t)(nb + ty + 8 * i) * DM + kb + tx] = (__bf16)tile[tx][ty + 8 * i];
}

// ---------------------------------------------------------------------------
// 128xBN bf16 GEMM, counted-vmcnt 2-deep pipeline, XOR-swizzled LDS.
// Out[m][n] = (A[m][k] * W[k][n] + bias[n]) * ascale
// vt=1: write transposed per-head layout Vt[bh][dk][token] (bf16 only).
// ---------------------------------------------------------------------------
struct Ptr3 { const __bf16* A; const __bf16* Bt; const float* bias; void* Out; float ascale; int vt; };
struct GemmArgs { Ptr3 p[3]; };

template <bool OUT_BF16, int BN>
__global__ __launch_bounds__(256) void gemm_tile(GemmArgs args) {
    constexpr int BGLD = BN / 32;           // B GLD16 issues per wave per tile
    constexpr int NJ   = BN / 32;           // B fragments per wave
    constexpr int NT   = DM / 64;           // 8 K-tiles
    __shared__ __bf16 Al[2][128][64];
    __shared__ __bf16 Bl[2][BN][64];
    const Ptr3 P = args.p[blockIdx.z];
    const int tid = threadIdx.x;
    const int lane = tid & 63, wid = tid >> 6;
    const int lq = lane & 15, hi = lane >> 4;
    const int m0 = blockIdx.x * 128, n0 = blockIdx.y * BN;
    const int wm = (wid >> 1) * 64, wn = (wid & 1) * (BN / 2);

    // --- staging pointers (pre-swizzled global source, linear LDS dest) ---
    const int lrow = lane >> 3, lslot = lane & 7;
    const __bf16* gaP[4];
#pragma unroll
    for (int i = 0; i < 4; ++i) {
        const int r = wid * 32 + i * 8 + lrow;
        const int s = lslot ^ ((r ^ (r >> 3)) & 7);
        gaP[i] = P.A + (size_t)(m0 + r) * DM + s * 8;
    }
    const __bf16* gbP[BGLD];
#pragma unroll
    for (int i = 0; i < BGLD; ++i) {
        const int r = wid * (BN / 4) + i * 8 + lrow;
        const int s = lslot ^ ((r ^ (r >> 3)) & 7);
        gbP[i] = P.Bt + (size_t)(n0 + r) * DM + s * 8;
    }
    auto stage = [&](int kt, int buf) {
        const int k0 = kt * 64;
#pragma unroll
        for (int i = 0; i < 4; ++i)
            GLD16(gaP[i] + k0, &Al[buf][wid * 32 + i * 8][0]);
#pragma unroll
        for (int i = 0; i < BGLD; ++i)
            GLD16(gbP[i] + k0, &Bl[buf][wid * (BN / 4) + i * 8][0]);
    };

    // --- read-side addresses (row base + swizzle) ---
    int baseA[4], swA[4];
#pragma unroll
    for (int i = 0; i < 4; ++i) {
        const int r = wm + i * 16 + lq;
        baseA[i] = r * 128;
        swA[i] = (((r ^ (r >> 3)) & 7) << 4);
    }
    int baseB[NJ], swB[NJ];
#pragma unroll
    for (int j = 0; j < NJ; ++j) {
        const int r = wn + j * 16 + lq;
        baseB[j] = r * 128;
        swB[j] = (((r ^ (r >> 3)) & 7) << 4);
    }

    f32x4 acc[4][NJ] = {};

    stage(0, 0);
    stage(1, 1);
    for (int kt = 0; kt < NT; ++kt) {
        const int cur = kt & 1;
        if (kt + 1 < NT) {
            if (BN == 128) { WAITVM(8); } else { WAITVM(6); }
        } else { WAITVM(0); }
        barrier_sync();
        const char* Ab = (const char*)&Al[cur][0][0];
        const char* Bb = (const char*)&Bl[cur][0][0];
        __builtin_amdgcn_s_setprio(1);
#pragma unroll
        for (int ks = 0; ks < 2; ++ks) {
            const int off = ks * 64 + hi * 16;
            bf16x8 af[4], bfv[NJ];
#pragma unroll
            for (int i = 0; i < 4; ++i)
                af[i] = *(const bf16x8*)(Ab + baseA[i] + (off ^ swA[i]));
#pragma unroll
            for (int j = 0; j < NJ; ++j)
                bfv[j] = *(const bf16x8*)(Bb + baseB[j] + (off ^ swB[j]));
#pragma unroll
            for (int i = 0; i < 4; ++i)
#pragma unroll
                for (int j = 0; j < NJ; ++j)
                    acc[i][j] = mfma16(af[i], bfv[j], acc[i][j]);
        }
        __builtin_amdgcn_s_setprio(0);
        if (kt + 2 < NT) {
            barrier_sync();
            stage(kt + 2, cur);
        }
    }

    const float* bias = P.bias;
    const float asc = P.ascale;
    if (OUT_BF16 && P.vt) {
        // transposed store: Vt[(b*H+head)*64 + dk][token], 4 tokens per 8B store
#pragma unroll
        for (int j = 0; j < NJ; ++j) {
            const int n = n0 + wn + j * 16 + lq;
            const int head = n >> 6, dk = n & 63;
            const float bv = bias[n];
#pragma unroll
            for (int i = 0; i < 4; ++i) {
                const int m = m0 + wm + i * 16 + hi * 4;
                const int b = m >> 12, q = m & (SEQ - 1);
                bf16x4 vv;
#pragma unroll
                for (int r = 0; r < 4; ++r) vv[r] = (__bf16)((acc[i][j][r] + bv) * asc);
                *(bf16x4*)&((__bf16*)P.Out)[((size_t)((b * HEADS + head) * DKH + dk)) * SEQ + q] = vv;
            }
        }
    } else {
#pragma unroll
        for (int j = 0; j < NJ; ++j) {
            const int n = n0 + wn + j * 16 + lq;
            const float bv = bias[n];
#pragma unroll
            for (int i = 0; i < 4; ++i) {
#pragma unroll
                for (int r = 0; r < 4; ++r) {
                    const int m = m0 + wm + i * 16 + hi * 4 + r;
                    const float v = (acc[i][j][r] + bv) * asc;
                    if (OUT_BF16) ((__bf16*)P.Out)[(size_t)m * DM + n] = (__bf16)v;
                    else          ((float*)P.Out)[(size_t)m * DM + n] = v;
                }
            }
        }
    }
}

// ---------------------------------------------------------------------------
// Flash attention, 32x32x16 MFMA, 4 waves x 32 q = 128 q per block.
// Round-3 sync structure (prefetch-at-top, single __syncthreads per tile).
// XCD-swizzled block mapping; l accumulated via MFMA with B = ones.
// ---------------------------------------------------------------------------
template <bool SPLIT>
__global__ __launch_bounds__(256, 4) void flash_attn5(const __bf16* __restrict__ Qp,
                                                      const __bf16* __restrict__ Kp,
                                                      const __bf16* __restrict__ Vt,
                                                      __bf16* __restrict__ O0,
                                                      __bf16* __restrict__ O1,
                                                      float* __restrict__ MLM,
                                                      float* __restrict__ MLL) {
    __shared__ __bf16 Kl[2][64][64];   // swizzled: slot ^= (row^(row>>3))&7
    __shared__ __bf16 Vl[2][64][64];
    __shared__ float  Lbuf[4][32];     // per-wave alpha broadcast

    const int tid = threadIdx.x, lane = tid & 63, w = tid >> 6;
    const int c = lane & 31, h = lane >> 5;

    // XCD-aware bijective swizzle: co-locate same-bh blocks on one XCD
    constexpr int NBLK = 32 * 16 * (SPLIT ? 2 : 1);
    constexpr int CPX = NBLK / 8;
    int fid = blockIdx.x + 32 * (blockIdx.y + 16 * blockIdx.z);
    fid = (fid & 7) * CPX + (fid >> 3);
    const int qt = fid & 31;
    const int bh = (fid >> 5) & 15;
    const int zz = SPLIT ? (fid >> 9) : 0;

    const int b = bh >> 3, hd = bh & 7;
    const int qbase = qt * 128 + w * 32;
    const int kvoff = SPLIT ? zz * (SEQ / 2) : 0;
    const int NT = SPLIT ? (SEQ / 2) / 64 : SEQ / 64;

    bf16x8 qf[4];
#pragma unroll
    for (int t = 0; t < 4; ++t)
        qf[t] = *(const bf16x8*)&Qp[(size_t)(b * SEQ + qbase + c) * DM + hd * DKH + 16 * t + 8 * h];

    const int r0 = w * 16 + (lane >> 3);
    const int r1 = r0 + 8;
    const int s0 = (lane & 7) ^ ((r0 ^ (r0 >> 3)) & 7);
    const int s1 = (lane & 7) ^ ((r1 ^ (r1 >> 3)) & 7);
    const __bf16* kg0 = Kp + (size_t)(b * SEQ + kvoff + r0) * DM + hd * DKH + s0 * 8;
    const __bf16* kg1 = Kp + (size_t)(b * SEQ + kvoff + r1) * DM + hd * DKH + s1 * 8;
    const __bf16* vg0 = Vt + (size_t)(bh * DKH + r0) * SEQ + kvoff + s0 * 8;
    const __bf16* vg1 = Vt + (size_t)(bh * DKH + r1) * SEQ + kvoff + s1 * 8;

    const int swz0 = (c ^ (c >> 3)) & 7;
    const int swz1 = ((32 + c) ^ ((32 + c) >> 3)) & 7;
    const int rowb0 = c * 128, rowb1 = (32 + c) * 128;
    const char* kb = (const char*)&Kl[0][0][0];
    const char* vb = (const char*)&Vl[0][0][0];

    auto stage = [&](int t, int buf) {
        const size_t ko = (size_t)t * 64 * DM, vo = (size_t)t * 64;
        GLD16(kg0 + ko, &Kl[buf][w * 16][0]);
        GLD16(kg1 + ko, &Kl[buf][w * 16 + 8][0]);
        GLD16(vg0 + vo, &Vl[buf][w * 16][0]);
        GLD16(vg1 + vo, &Vl[buf][w * 16 + 8][0]);
    };

    bf16x8 vone;
#pragma unroll
    for (int j = 0; j < 8; ++j) vone[j] = (__bf16)1.0f;

    f32x16 acc0 = {}, acc1 = {}, lacc = {};
    float m_run = -__builtin_inff();

    stage(0, 0);
    __syncthreads();

    for (int t = 0; t < NT; ++t) {
        const int cur = t & 1;
        if (t + 1 < NT) stage(t + 1, cur ^ 1);   // prefetch next tile
        const char* kc = kb + cur * 8192;
        const char* vc = vb + cur * 8192;

        // ---- QK^T
        f32x16 sa = {}, sb = {};
        __builtin_amdgcn_s_setprio(1);
#pragma unroll
        for (int tt = 0; tt < 4; ++tt) {
            bf16x8 kf0 = *(const bf16x8*)(kc + rowb0 + (((2 * tt + h) ^ swz0) << 4));
            sa = mfma32(kf0, qf[tt], sa);
            bf16x8 kf1 = *(const bf16x8*)(kc + rowb1 + (((2 * tt + h) ^ swz1) << 4));
            sb = mfma32(kf1, qf[tt], sb);
        }
        __builtin_amdgcn_s_setprio(0);

        // ---- online softmax (exp2 domain), defer-max THR=8
        float mx = fmaxf(sa[0], sa[1]);
#pragma unroll
        for (int r = 2; r < 16; r += 2) mx = fmaxf(mx, fmaxf(sa[r], sa[r + 1]));
#pragma unroll
        for (int r = 0; r < 16; r += 2) mx = fmaxf(mx, fmaxf(sb[r], sb[r + 1]));
        mx = fmaxf(mx, __shfl_xor(mx, 32));
        if (!__all(mx <= m_run + 8.f)) {
            const float mnew = fmaxf(m_run, mx);
            const float al = __builtin_amdgcn_exp2f(m_run - mnew);
            m_run = mnew;
            if (lane < 32) Lbuf[w][lane] = al;
#pragma unroll
            for (int r = 0; r < 16; ++r) {
                const float a2 = Lbuf[w][(r & 3) + 8 * (r >> 2) + 4 * h];
                acc0[r] *= a2; acc1[r] *= a2; lacc[r] *= a2;
            }
        }

        // ---- exp2 + pack to bf16 pairs
        int ua[4][2], ub[4][2];
#pragma unroll
        for (int q4 = 0; q4 < 4; ++q4) {
            float p0 = __builtin_amdgcn_exp2f(sa[4 * q4 + 0] - m_run);
            float p1 = __builtin_amdgcn_exp2f(sa[4 * q4 + 1] - m_run);
            float p2 = __builtin_amdgcn_exp2f(sa[4 * q4 + 2] - m_run);
            float p3 = __builtin_amdgcn_exp2f(sa[4 * q4 + 3] - m_run);
            bf16x2 t0; t0[0] = (__bf16)p0; t0[1] = (__bf16)p1;
            bf16x2 t1; t1[0] = (__bf16)p2; t1[1] = (__bf16)p3;
            ua[q4][0] = __builtin_bit_cast(int, t0);
            ua[q4][1] = __builtin_bit_cast(int, t1);
        }
#pragma unroll
        for (int q4 = 0; q4 < 4; ++q4) {
            float p0 = __builtin_amdgcn_exp2f(sb[4 * q4 + 0] - m_run);
            float p1 = __builtin_amdgcn_exp2f(sb[4 * q4 + 1] - m_run);
            float p2 = __builtin_amdgcn_exp2f(sb[4 * q4 + 2] - m_run);
            float p3 = __builtin_amdgcn_exp2f(sb[4 * q4 + 3] - m_run);
            bf16x2 t0; t0[0] = (__bf16)p0; t0[1] = (__bf16)p1;
            bf16x2 t1; t1[0] = (__bf16)p2; t1[1] = (__bf16)p3;
            ub[q4][0] = __builtin_bit_cast(int, t0);
            ub[q4][1] = __builtin_bit_cast(int, t1);
        }

        // ---- PV (+ l accumulation via MFMA with B = ones)
#pragma unroll
        for (int tg = 0; tg < 4; ++tg) {
            int x0, y0, x1, y1;
            if (tg < 2) {
                x0 = ua[2 * tg][0]; y0 = ua[2 * tg + 1][0];
                x1 = ua[2 * tg][1]; y1 = ua[2 * tg + 1][1];
            } else {
                x0 = ub[2 * (tg - 2)][0]; y0 = ub[2 * (tg - 2) + 1][0];
                x1 = ub[2 * (tg - 2)][1]; y1 = ub[2 * (tg - 2) + 1][1];
            }
            asm("v_permlane32_swap_b32 %0, %1" : "+v"(x0), "+v"(y0));
            asm("v_permlane32_swap_b32 %0, %1" : "+v"(x1), "+v"(y1));
            union { int i4[4]; bf16x8 v; } pf;
            pf.i4[0] = x0; pf.i4[1] = x1; pf.i4[2] = y0; pf.i4[3] = y1;
            bf16x8 vf0 = *(const bf16x8*)(vc + rowb0 + (((2 * tg + h) ^ swz0) << 4));
            bf16x8 vf1 = *(const bf16x8*)(vc + rowb1 + (((2 * tg + h) ^ swz1) << 4));
            __builtin_amdgcn_s_setprio(1);
            acc0 = mfma32(pf.v, vf0, acc0);
            acc1 = mfma32(pf.v, vf1, acc1);
            lacc = mfma32(pf.v, vone, lacc);
            __builtin_amdgcn_s_setprio(0);
        }
        __syncthreads();   // drains this tile's prefetch DMA + all LDS reads
    }

    if (SPLIT) {
        __bf16* pp = zz ? O1 : O0;
#pragma unroll
        for (int r = 0; r < 16; ++r) {
            const int qr = (r & 3) + 8 * (r >> 2) + 4 * h;
            const size_t off = (size_t)(b * SEQ + qbase + qr) * DM + hd * DKH;
            pp[off + c]      = (__bf16)acc0[r];
            pp[off + 32 + c] = (__bf16)acc1[r];
        }
        const int zo = zz * 16 + bh;
        if (h == 0) MLM[(size_t)zo * SEQ + qbase + c] = m_run;
        if (c == 0) {
#pragma unroll
            for (int r = 0; r < 16; ++r) {
                const int qr = (r & 3) + 8 * (r >> 2) + 4 * h;
                MLL[(size_t)zo * SEQ + qbase + qr] = lacc[r];
            }
        }
    } else {
        __bf16* outp = O0 + (size_t)(b * SEQ + qbase) * DM + hd * DKH;
#pragma unroll
        for (int r = 0; r < 16; ++r) {
            const int qr = (r & 3) + 8 * (r >> 2) + 4 * h;
            const float li = 1.f / lacc[r];
            outp[(size_t)qr * DM + c]      = (__bf16)(acc0[r] * li);
            outp[(size_t)qr * DM + 32 + c] = (__bf16)(acc1[r] * li);
        }
    }
}

// ---------------------------------------------------------------------------
// Combine the two kv-half partials:  Ctx = (P0*e0 + P1*e1) / (l0*e0 + l1*e1)
// ---------------------------------------------------------------------------
__global__ __launch_bounds__(256) void combine(const __bf16* __restrict__ P0,
                                               const __bf16* __restrict__ P1,
                                               const float* __restrict__ MLM,
                                               const float* __restrict__ MLL,
                                               __bf16* __restrict__ Ctx) {
    const int row = blockIdx.x;             // b*SEQ + q
    const int b = row >> 12, q = row & (SEQ - 1);
    const int col = threadIdx.x * 2;
    const int head = col >> 6;
    const int bh = b * HEADS + head;
    const float m0 = MLM[(size_t)bh * SEQ + q];
    const float m1 = MLM[(size_t)(16 + bh) * SEQ + q];
    const float l0 = MLL[(size_t)bh * SEQ + q];
    const float l1 = MLL[(size_t)(16 + bh) * SEQ + q];
    const float m = fmaxf(m0, m1);
    const float e0 = __builtin_amdgcn_exp2f(m0 - m);
    const float e1 = __builtin_amdgcn_exp2f(m1 - m);
    const float inv = 1.f / (l0 * e0 + l1 * e1);
    const float f0 = e0 * inv, f1 = e1 * inv;
    const size_t idx = (size_t)row * DM + col;
    bf16x2 a = *(const bf16x2*)&P0[idx];
    bf16x2 bb = *(const bf16x2*)&P1[idx];
    bf16x2 o;
    o[0] = (__bf16)((float)a[0] * f0 + (float)bb[0] * f1);
    o[1] = (__bf16)((float)a[1] * f0 + (float)bb[1] * f1);
    *(bf16x2*)&Ctx[idx] = o;
}

// ---------------------------------------------------------------------------
extern "C" void kernel_launch(void* const* d_in, const int* in_sizes, int n_in,
                              void* d_out, int out_size, void* d_ws, size_t ws_size,
                              hipStream_t stream) {
    (void)in_sizes; (void)n_in; (void)out_size;
    const float* query = (const float*)d_in[0];
    const float* key_  = (const float*)d_in[1];
    const float* value = (const float*)d_in[2];
    const float* Wq = (const float*)d_in[3];
    const float* bq = (const float*)d_in[4];
    const float* Wk = (const float*)d_in[5];
    const float* bk = (const float*)d_in[6];
    const float* Wv = (const float*)d_in[7];
    const float* bv = (const float*)d_in[8];
    const float* Wo = (const float*)d_in[9];
    const float* bo = (const float*)d_in[10];

    char* ws = (char*)d_ws;
    const size_t WSZ = (size_t)512 * 1024;        // per transposed weight
    const size_t XSZ = (size_t)8 * 1024 * 1024;   // per [8192][512] bf16 buffer
    const float QSC = 0.125f * 1.4426950408889634f;  // 1/sqrt(dk) * log2(e)
    if (ws_size < 4 * WSZ + 7 * XSZ) return;      // 58 MiB needed (proven available)

    __bf16* Wtq = (__bf16*)(ws);
    __bf16* Wtk = (__bf16*)(ws + WSZ);
    __bf16* Wtv = (__bf16*)(ws + 2 * WSZ);
    __bf16* Wto = (__bf16*)(ws + 3 * WSZ);
    char* xb = ws + 4 * WSZ;
    __bf16* Qb = (__bf16*)(xb);                 // -> P0 after projections
    __bf16* Kb = (__bf16*)(xb + XSZ);           // -> P1
    __bf16* Vb = (__bf16*)(xb + 2 * XSZ);       // -> MLM/MLL
    __bf16* Qp = (__bf16*)(xb + 3 * XSZ);
    __bf16* Kp = (__bf16*)(xb + 4 * XSZ);
    __bf16* Vt = (__bf16*)(xb + 5 * XSZ);       // written directly by V-proj GEMM
    __bf16* Ctx = (__bf16*)(xb + 6 * XSZ);
    __bf16* P0 = Qb;
    __bf16* P1 = Kb;
    float* MLM = (float*)Vb;          // 2*16*4096 floats = 512 KB
    float* MLL = MLM + 2 * 16 * SEQ;  // 512 KB

    Cvt3 cv;
    cv.s[0] = query; cv.s[1] = key_; cv.s[2] = value;
    cv.d[0] = Qb; cv.d[1] = Kb; cv.d[2] = Vb;
    convert_x3<<<dim3(2048, 3), 256, 0, stream>>>(cv);

    WtAll wa;
    wa.W[0] = Wq; wa.W[1] = Wk; wa.W[2] = Wv; wa.W[3] = Wo;
    wa.Wt[0] = Wtq; wa.Wt[1] = Wtk; wa.Wt[2] = Wtv; wa.Wt[3] = Wto;
    wt_convert_all<<<dim3(16, 16, 4), 256, 0, stream>>>(wa);

    GemmArgs qa;
    qa.p[0] = {Qb, Wtq, bq, Qp, QSC, 0};
    qa.p[1] = {Kb, Wtk, bk, Kp, 1.0f, 0};
    qa.p[2] = {Vb, Wtv, bv, Vt, 1.0f, 1};       // V-proj writes Vt directly
    gemm_tile<true, 128><<<dim3(64, 4, 3), 256, 0, stream>>>(qa);

    flash_attn5<true><<<dim3(SEQ / 128, BATCH * HEADS, 2), 256, 0, stream>>>(
        Qp, Kp, Vt, P0, P1, MLM, MLL);

    combine<<<dim3(BATCH * SEQ), 256, 0, stream>>>(P0, P1, MLM, MLL, Ctx);

    GemmArgs oa;
    oa.p[0] = {Ctx, Wto, bo, d_out, 1.0f, 0};
    oa.p[1] = oa.p[0]; oa.p[2] = oa.p[0];
    gemm_tile<false, 64><<<dim3(64, 8, 1), 256, 0, stream>>>(oa);
}

// Round 7
// 243.831 us; speedup vs baseline: 1.0944x; 1.0499x over previous
//
#include <hip/hip_runtime.h>
#include <hip/hip_bf16.h>

#define DM   512
#define HEADS 8
#define DKH  64
#define BATCH 2
#define SEQ  4096

typedef float  f32x4  __attribute__((ext_vector_type(4)));
typedef float  f32x16 __attribute__((ext_vector_type(16)));
typedef __bf16 bf16x8 __attribute__((ext_vector_type(8)));
typedef __bf16 bf16x4 __attribute__((ext_vector_type(4)));
typedef __bf16 bf16x2 __attribute__((ext_vector_type(2)));

static __device__ __forceinline__ f32x4 mfma16(bf16x8 a, bf16x8 b, f32x4 c) {
    return __builtin_amdgcn_mfma_f32_16x16x32_bf16(a, b, c, 0, 0, 0);
}
static __device__ __forceinline__ f32x16 mfma32(bf16x8 a, bf16x8 b, f32x16 c) {
    return __builtin_amdgcn_mfma_f32_32x32x16_bf16(a, b, c, 0, 0, 0);
}

#define GLD16(gp, lp) __builtin_amdgcn_global_load_lds( \
    (const __attribute__((address_space(1))) void*)(gp), \
    (__attribute__((address_space(3))) void*)(lp), 16, 0, 0)

#define WAITVM(n) asm volatile("s_waitcnt vmcnt(" #n ")" ::: "memory")

static __device__ __forceinline__ void barrier_sync() {
    __builtin_amdgcn_sched_barrier(0);
    asm volatile("" ::: "memory");
    __builtin_amdgcn_s_barrier();
    asm volatile("" ::: "memory");
    __builtin_amdgcn_sched_barrier(0);
}

// ---------------------------------------------------------------------------
// prep_all: fused fp32->bf16 activation convert (blocks 0..6143) and
// weight transpose+convert W[k][n] -> Wt[n][k] (blocks 6144..7167).
// ---------------------------------------------------------------------------
struct PrepArgs { const float* s[3]; __bf16* d[3]; const float* W[4]; __bf16* Wt[4]; };

__global__ __launch_bounds__(256) void prep_all(PrepArgs a) {
    __shared__ float tile[32][33];
    const int bid = blockIdx.x;
    if (bid < 6144) {
        const int t = bid >> 11, cb = bid & 2047;
        const float* s = a.s[t];
        __bf16* d = a.d[t];
        const size_t i = ((size_t)cb * 256 + threadIdx.x) * 8;
        f32x4 f0 = *(const f32x4*)&s[i];
        f32x4 f1 = *(const f32x4*)&s[i + 4];
        bf16x8 v;
        v[0] = (__bf16)f0[0]; v[1] = (__bf16)f0[1]; v[2] = (__bf16)f0[2]; v[3] = (__bf16)f0[3];
        v[4] = (__bf16)f1[0]; v[5] = (__bf16)f1[1]; v[6] = (__bf16)f1[2]; v[7] = (__bf16)f1[3];
        *(bf16x8*)&d[i] = v;
    } else {
        const int r = bid - 6144;                 // 0..1023
        const int wsel = r >> 8, tl = r & 255;
        const float* W = a.W[wsel];
        __bf16* Wt = a.Wt[wsel];
        const int nb = (tl & 15) * 32, kb = (tl >> 4) * 32;
        const int tx = threadIdx.x & 31, ty = threadIdx.x >> 5;
#pragma unroll
        for (int i = 0; i < 4; ++i)
            tile[ty + 8 * i][tx] = W[(size_t)(kb + ty + 8 * i) * DM + nb + tx];
        __syncthreads();
#pragma unroll
        for (int i = 0; i < 4; ++i)
            Wt[(size_t)(nb + ty + 8 * i) * DM + kb + tx] = (__bf16)tile[tx][ty + 8 * i];
    }
}

// ---------------------------------------------------------------------------
// 128x128 bf16 GEMM (QKV projections), counted-vmcnt 2-deep pipeline,
// XOR-swizzled LDS.  Out[m][n] = (A*W + bias)*ascale.
// vt=1: write transposed per-head layout Vt[bh][dk][token].
// ---------------------------------------------------------------------------
struct Ptr3 { const __bf16* A; const __bf16* Bt; const float* bias; void* Out; float ascale; int vt; };
struct GemmArgs { Ptr3 p[3]; };

__global__ __launch_bounds__(256) void gemm_qkv(GemmArgs args) {
    constexpr int BN = 128, BGLD = 4, NJ = 4, NT = DM / 64;
    __shared__ __bf16 Al[2][128][64];
    __shared__ __bf16 Bl[2][BN][64];
    const Ptr3 P = args.p[blockIdx.z];
    const int tid = threadIdx.x;
    const int lane = tid & 63, wid = tid >> 6;
    const int lq = lane & 15, hi = lane >> 4;
    const int m0 = blockIdx.x * 128, n0 = blockIdx.y * BN;
    const int wm = (wid >> 1) * 64, wn = (wid & 1) * (BN / 2);

    const int lrow = lane >> 3, lslot = lane & 7;
    const __bf16* gaP[4];
#pragma unroll
    for (int i = 0; i < 4; ++i) {
        const int r = wid * 32 + i * 8 + lrow;
        const int s = lslot ^ ((r ^ (r >> 3)) & 7);
        gaP[i] = P.A + (size_t)(m0 + r) * DM + s * 8;
    }
    const __bf16* gbP[BGLD];
#pragma unroll
    for (int i = 0; i < BGLD; ++i) {
        const int r = wid * (BN / 4) + i * 8 + lrow;
        const int s = lslot ^ ((r ^ (r >> 3)) & 7);
        gbP[i] = P.Bt + (size_t)(n0 + r) * DM + s * 8;
    }
    auto stage = [&](int kt, int buf) {
        const int k0 = kt * 64;
#pragma unroll
        for (int i = 0; i < 4; ++i)
            GLD16(gaP[i] + k0, &Al[buf][wid * 32 + i * 8][0]);
#pragma unroll
        for (int i = 0; i < BGLD; ++i)
            GLD16(gbP[i] + k0, &Bl[buf][wid * (BN / 4) + i * 8][0]);
    };

    int baseA[4], swA[4];
#pragma unroll
    for (int i = 0; i < 4; ++i) {
        const int r = wm + i * 16 + lq;
        baseA[i] = r * 128;
        swA[i] = (((r ^ (r >> 3)) & 7) << 4);
    }
    int baseB[NJ], swB[NJ];
#pragma unroll
    for (int j = 0; j < NJ; ++j) {
        const int r = wn + j * 16 + lq;
        baseB[j] = r * 128;
        swB[j] = (((r ^ (r >> 3)) & 7) << 4);
    }

    f32x4 acc[4][NJ] = {};

    stage(0, 0);
    stage(1, 1);
    for (int kt = 0; kt < NT; ++kt) {
        const int cur = kt & 1;
        if (kt + 1 < NT) { WAITVM(8); } else { WAITVM(0); }
        barrier_sync();
        const char* Ab = (const char*)&Al[cur][0][0];
        const char* Bb = (const char*)&Bl[cur][0][0];
        __builtin_amdgcn_s_setprio(1);
#pragma unroll
        for (int ks = 0; ks < 2; ++ks) {
            const int off = ks * 64 + hi * 16;
            bf16x8 af[4], bfv[NJ];
#pragma unroll
            for (int i = 0; i < 4; ++i)
                af[i] = *(const bf16x8*)(Ab + baseA[i] + (off ^ swA[i]));
#pragma unroll
            for (int j = 0; j < NJ; ++j)
                bfv[j] = *(const bf16x8*)(Bb + baseB[j] + (off ^ swB[j]));
#pragma unroll
            for (int i = 0; i < 4; ++i)
#pragma unroll
                for (int j = 0; j < NJ; ++j)
                    acc[i][j] = mfma16(af[i], bfv[j], acc[i][j]);
        }
        __builtin_amdgcn_s_setprio(0);
        if (kt + 2 < NT) {
            barrier_sync();
            stage(kt + 2, cur);
        }
    }

    const float* bias = P.bias;
    const float asc = P.ascale;
    if (P.vt) {
#pragma unroll
        for (int j = 0; j < NJ; ++j) {
            const int n = n0 + wn + j * 16 + lq;
            const int head = n >> 6, dk = n & 63;
            const float bv = bias[n];
#pragma unroll
            for (int i = 0; i < 4; ++i) {
                const int m = m0 + wm + i * 16 + hi * 4;
                const int b = m >> 12, q = m & (SEQ - 1);
                bf16x4 vv;
#pragma unroll
                for (int r = 0; r < 4; ++r) vv[r] = (__bf16)((acc[i][j][r] + bv) * asc);
                *(bf16x4*)&((__bf16*)P.Out)[((size_t)((b * HEADS + head) * DKH + dk)) * SEQ + q] = vv;
            }
        }
    } else {
#pragma unroll
        for (int j = 0; j < NJ; ++j) {
            const int n = n0 + wn + j * 16 + lq;
            const float bv = bias[n];
#pragma unroll
            for (int i = 0; i < 4; ++i) {
#pragma unroll
                for (int r = 0; r < 4; ++r) {
                    const int m = m0 + wm + i * 16 + hi * 4 + r;
                    ((__bf16*)P.Out)[(size_t)m * DM + n] = (__bf16)((acc[i][j][r] + bv) * asc);
                }
            }
        }
    }
}

// ---------------------------------------------------------------------------
// Flash attention, 32x32x16 MFMA, 4 waves x 32 q = 128 q per block.
// Round-3 sync structure; XCD swizzle; VALU lsum (lacc-via-MFMA reverted).
// ---------------------------------------------------------------------------
__global__ __launch_bounds__(256, 4) void flash_attn6(const __bf16* __restrict__ Qp,
                                                      const __bf16* __restrict__ Kp,
                                                      const __bf16* __restrict__ Vt,
                                                      __bf16* __restrict__ O0,
                                                      __bf16* __restrict__ O1,
                                                      float* __restrict__ MLM,
                                                      float* __restrict__ MLL) {
    __shared__ __bf16 Kl[2][64][64];   // swizzled: slot ^= (row^(row>>3))&7
    __shared__ __bf16 Vl[2][64][64];
    __shared__ float  Lbuf[4][32];

    const int tid = threadIdx.x, lane = tid & 63, w = tid >> 6;
    const int c = lane & 31, h = lane >> 5;

    // XCD-aware bijective swizzle (1024 blocks, 1024%8==0)
    constexpr int NBLK = 32 * 16 * 2;
    constexpr int CPX = NBLK / 8;
    int fid = blockIdx.x + 32 * (blockIdx.y + 16 * blockIdx.z);
    fid = (fid & 7) * CPX + (fid >> 3);
    const int qt = fid & 31;
    const int bh = (fid >> 5) & 15;
    const int zz = fid >> 9;

    const int b = bh >> 3, hd = bh & 7;
    const int qbase = qt * 128 + w * 32;
    const int kvoff = zz * (SEQ / 2);
    const int NT = (SEQ / 2) / 64;

    bf16x8 qf[4];
#pragma unroll
    for (int t = 0; t < 4; ++t)
        qf[t] = *(const bf16x8*)&Qp[(size_t)(b * SEQ + qbase + c) * DM + hd * DKH + 16 * t + 8 * h];

    const int r0 = w * 16 + (lane >> 3);
    const int r1 = r0 + 8;
    const int s0 = (lane & 7) ^ ((r0 ^ (r0 >> 3)) & 7);
    const int s1 = (lane & 7) ^ ((r1 ^ (r1 >> 3)) & 7);
    const __bf16* kg0 = Kp + (size_t)(b * SEQ + kvoff + r0) * DM + hd * DKH + s0 * 8;
    const __bf16* kg1 = Kp + (size_t)(b * SEQ + kvoff + r1) * DM + hd * DKH + s1 * 8;
    const __bf16* vg0 = Vt + (size_t)(bh * DKH + r0) * SEQ + kvoff + s0 * 8;
    const __bf16* vg1 = Vt + (size_t)(bh * DKH + r1) * SEQ + kvoff + s1 * 8;

    const int swz0 = (c ^ (c >> 3)) & 7;
    const int swz1 = ((32 + c) ^ ((32 + c) >> 3)) & 7;
    const int rowb0 = c * 128, rowb1 = (32 + c) * 128;
    const char* kb = (const char*)&Kl[0][0][0];
    const char* vb = (const char*)&Vl[0][0][0];

    auto stage = [&](int t, int buf) {
        const size_t ko = (size_t)t * 64 * DM, vo = (size_t)t * 64;
        GLD16(kg0 + ko, &Kl[buf][w * 16][0]);
        GLD16(kg1 + ko, &Kl[buf][w * 16 + 8][0]);
        GLD16(vg0 + vo, &Vl[buf][w * 16][0]);
        GLD16(vg1 + vo, &Vl[buf][w * 16 + 8][0]);
    };

    f32x16 acc0 = {}, acc1 = {};
    float m_run = -__builtin_inff(), l_run = 0.f;

    stage(0, 0);
    __syncthreads();

    for (int t = 0; t < NT; ++t) {
        const int cur = t & 1;
        if (t + 1 < NT) stage(t + 1, cur ^ 1);   // prefetch next tile
        const char* kc = kb + cur * 8192;
        const char* vc = vb + cur * 8192;

        // ---- QK^T
        f32x16 sa = {}, sb = {};
        __builtin_amdgcn_s_setprio(1);
#pragma unroll
        for (int tt = 0; tt < 4; ++tt) {
            bf16x8 kf0 = *(const bf16x8*)(kc + rowb0 + (((2 * tt + h) ^ swz0) << 4));
            sa = mfma32(kf0, qf[tt], sa);
            bf16x8 kf1 = *(const bf16x8*)(kc + rowb1 + (((2 * tt + h) ^ swz1) << 4));
            sb = mfma32(kf1, qf[tt], sb);
        }
        __builtin_amdgcn_s_setprio(0);

        // ---- online softmax (exp2 domain), defer-max THR=8
        float mx = fmaxf(sa[0], sa[1]);
#pragma unroll
        for (int r = 2; r < 16; r += 2) mx = fmaxf(mx, fmaxf(sa[r], sa[r + 1]));
#pragma unroll
        for (int r = 0; r < 16; r += 2) mx = fmaxf(mx, fmaxf(sb[r], sb[r + 1]));
        mx = fmaxf(mx, __shfl_xor(mx, 32));
        if (!__all(mx <= m_run + 8.f)) {
            const float mnew = fmaxf(m_run, mx);
            const float al = __builtin_amdgcn_exp2f(m_run - mnew);
            m_run = mnew;
            l_run *= al;
            if (lane < 32) Lbuf[w][lane] = al;
#pragma unroll
            for (int r = 0; r < 16; ++r) {
                const float a2 = Lbuf[w][(r & 3) + 8 * (r >> 2) + 4 * h];
                acc0[r] *= a2; acc1[r] *= a2;
            }
        }

        // ---- exp2 + pack to bf16 pairs, VALU row-sum
        float ls = 0.f;
        int ua[4][2], ub[4][2];
#pragma unroll
        for (int q4 = 0; q4 < 4; ++q4) {
            float p0 = __builtin_amdgcn_exp2f(sa[4 * q4 + 0] - m_run);
            float p1 = __builtin_amdgcn_exp2f(sa[4 * q4 + 1] - m_run);
            float p2 = __builtin_amdgcn_exp2f(sa[4 * q4 + 2] - m_run);
            float p3 = __builtin_amdgcn_exp2f(sa[4 * q4 + 3] - m_run);
            ls += p0 + p1 + p2 + p3;
            bf16x2 t0; t0[0] = (__bf16)p0; t0[1] = (__bf16)p1;
            bf16x2 t1; t1[0] = (__bf16)p2; t1[1] = (__bf16)p3;
            ua[q4][0] = __builtin_bit_cast(int, t0);
            ua[q4][1] = __builtin_bit_cast(int, t1);
        }
#pragma unroll
        for (int q4 = 0; q4 < 4; ++q4) {
            float p0 = __builtin_amdgcn_exp2f(sb[4 * q4 + 0] - m_run);
            float p1 = __builtin_amdgcn_exp2f(sb[4 * q4 + 1] - m_run);
            float p2 = __builtin_amdgcn_exp2f(sb[4 * q4 + 2] - m_run);
            float p3 = __builtin_amdgcn_exp2f(sb[4 * q4 + 3] - m_run);
            ls += p0 + p1 + p2 + p3;
            bf16x2 t0; t0[0] = (__bf16)p0; t0[1] = (__bf16)p1;
            bf16x2 t1; t1[0] = (__bf16)p2; t1[1] = (__bf16)p3;
            ub[q4][0] = __builtin_bit_cast(int, t0);
            ub[q4][1] = __builtin_bit_cast(int, t1);
        }
        ls += __shfl_xor(ls, 32);
        l_run += ls;

        // ---- PV
#pragma unroll
        for (int tg = 0; tg < 4; ++tg) {
            int x0, y0, x1, y1;
            if (tg < 2) {
                x0 = ua[2 * tg][0]; y0 = ua[2 * tg + 1][0];
                x1 = ua[2 * tg][1]; y1 = ua[2 * tg + 1][1];
            } else {
                x0 = ub[2 * (tg - 2)][0]; y0 = ub[2 * (tg - 2) + 1][0];
                x1 = ub[2 * (tg - 2)][1]; y1 = ub[2 * (tg - 2) + 1][1];
            }
            asm("v_permlane32_swap_b32 %0, %1" : "+v"(x0), "+v"(y0));
            asm("v_permlane32_swap_b32 %0, %1" : "+v"(x1), "+v"(y1));
            union { int i4[4]; bf16x8 v; } pf;
            pf.i4[0] = x0; pf.i4[1] = x1; pf.i4[2] = y0; pf.i4[3] = y1;
            bf16x8 vf0 = *(const bf16x8*)(vc + rowb0 + (((2 * tg + h) ^ swz0) << 4));
            bf16x8 vf1 = *(const bf16x8*)(vc + rowb1 + (((2 * tg + h) ^ swz1) << 4));
            __builtin_amdgcn_s_setprio(1);
            acc0 = mfma32(pf.v, vf0, acc0);
            acc1 = mfma32(pf.v, vf1, acc1);
            __builtin_amdgcn_s_setprio(0);
        }
        __syncthreads();   // drains this tile's prefetch DMA + all LDS reads
    }

    // ---- split epilogue: unnormalized partials + (m, l) per q-row
    __bf16* pp = zz ? O1 : O0;
#pragma unroll
    for (int r = 0; r < 16; ++r) {
        const int qr = (r & 3) + 8 * (r >> 2) + 4 * h;
        const size_t off = (size_t)(b * SEQ + qbase + qr) * DM + hd * DKH;
        pp[off + c]      = (__bf16)acc0[r];
        pp[off + 32 + c] = (__bf16)acc1[r];
    }
    const int zo = zz * 16 + bh;
    if (h == 0) {
        MLM[(size_t)zo * SEQ + qbase + c] = m_run;
        MLL[(size_t)zo * SEQ + qbase + c] = l_run;
    }
}

// ---------------------------------------------------------------------------
// Output projection with FUSED split-kv combine in the A-staging:
// A[m][k] = (P0[m][k]*f0(m,head) + P1[m][k]*f1(m,head)),  head = k/64.
// Out[m][n] = A*Wo + bo  (fp32).  Single-buffered LDS, 2 syncs/tile.
// ---------------------------------------------------------------------------
__global__ __launch_bounds__(256) void gemm_out(const __bf16* __restrict__ P0,
                                                const __bf16* __restrict__ P1,
                                                const float* __restrict__ MLM,
                                                const float* __restrict__ MLL,
                                                const __bf16* __restrict__ Bt,
                                                const float* __restrict__ bias,
                                                float* __restrict__ Out) {
    constexpr int BN = 64, NJ = 2, NT = DM / 64;
    __shared__ __bf16 Al[128][64];
    __shared__ __bf16 Bl[BN][64];
    const int tid = threadIdx.x;
    const int lane = tid & 63, wid = tid >> 6;
    const int lq = lane & 15, hi = lane >> 4;
    const int m0 = blockIdx.x * 128, n0 = blockIdx.y * BN;
    const int wm = (wid >> 1) * 64, wn = (wid & 1) * (BN / 2);

    const int lrow = lane >> 3, lslot = lane & 7;
    // A rows this lane stages (4 of them) + their combine metadata
    int arow[4]; size_t abase[4];
#pragma unroll
    for (int i = 0; i < 4; ++i) {
        arow[i] = wid * 32 + i * 8 + lrow;
        abase[i] = (size_t)(m0 + arow[i]) * DM + lslot * 8;
    }
    // B staging via GLD16 (pre-swizzled source)
    const __bf16* gbP[2];
#pragma unroll
    for (int i = 0; i < 2; ++i) {
        const int r = wid * 16 + i * 8 + lrow;
        const int s = lslot ^ ((r ^ (r >> 3)) & 7);
        gbP[i] = Bt + (size_t)(n0 + r) * DM + s * 8;
    }

    int baseA[4], swA[4];
#pragma unroll
    for (int i = 0; i < 4; ++i) {
        const int r = wm + i * 16 + lq;
        baseA[i] = r * 128;
        swA[i] = (((r ^ (r >> 3)) & 7) << 4);
    }
    int baseB[NJ], swB[NJ];
#pragma unroll
    for (int j = 0; j < NJ; ++j) {
        const int r = wn + j * 16 + lq;
        baseB[j] = r * 128;
        swB[j] = (((r ^ (r >> 3)) & 7) << 4);
    }

    f32x4 acc[4][NJ] = {};

    for (int kt = 0; kt < NT; ++kt) {
        const int k0 = kt * 64;
        // --- A: load partials + combine in registers (head == kt) ---
        bf16x8 aw[4];
#pragma unroll
        for (int i = 0; i < 4; ++i) {
            const int m = m0 + arow[i];
            const int b = m >> 12, q = m & (SEQ - 1);
            const int bh = b * HEADS + kt;
            bf16x8 a0 = *(const bf16x8*)&P0[abase[i] + k0];
            bf16x8 a1 = *(const bf16x8*)&P1[abase[i] + k0];
            const float mv0 = MLM[(size_t)bh * SEQ + q];
            const float mv1 = MLM[(size_t)(16 + bh) * SEQ + q];
            const float lv0 = MLL[(size_t)bh * SEQ + q];
            const float lv1 = MLL[(size_t)(16 + bh) * SEQ + q];
            const float mm = fmaxf(mv0, mv1);
            const float e0 = __builtin_amdgcn_exp2f(mv0 - mm);
            const float e1 = __builtin_amdgcn_exp2f(mv1 - mm);
            const float inv = 1.f / (lv0 * e0 + lv1 * e1);
            const float f0 = e0 * inv, f1 = e1 * inv;
            bf16x8 o;
#pragma unroll
            for (int j = 0; j < 8; ++j)
                o[j] = (__bf16)((float)a0[j] * f0 + (float)a1[j] * f1);
            aw[i] = o;
        }
        if (kt) __syncthreads();            // prev tile fully consumed
        // --- B DMA + A LDS write (swizzled) ---
#pragma unroll
        for (int i = 0; i < 2; ++i)
            GLD16(gbP[i] + k0, &Bl[wid * 16 + i * 8][0]);
#pragma unroll
        for (int i = 0; i < 4; ++i) {
            const int r = arow[i];
            char* dst = (char*)&Al[0][0] + r * 128 + ((lslot ^ ((r ^ (r >> 3)) & 7)) << 4);
            *(bf16x8*)dst = aw[i];
        }
        __syncthreads();                    // drains B DMA + A writes

        const char* Ab = (const char*)&Al[0][0];
        const char* Bb = (const char*)&Bl[0][0];
        __builtin_amdgcn_s_setprio(1);
#pragma unroll
        for (int ks = 0; ks < 2; ++ks) {
            const int off = ks * 64 + hi * 16;
            bf16x8 af[4], bfv[NJ];
#pragma unroll
            for (int i = 0; i < 4; ++i)
                af[i] = *(const bf16x8*)(Ab + baseA[i] + (off ^ swA[i]));
#pragma unroll
            for (int j = 0; j < NJ; ++j)
                bfv[j] = *(const bf16x8*)(Bb + baseB[j] + (off ^ swB[j]));
#pragma unroll
            for (int i = 0; i < 4; ++i)
#pragma unroll
                for (int j = 0; j < NJ; ++j)
                    acc[i][j] = mfma16(af[i], bfv[j], acc[i][j]);
        }
        __builtin_amdgcn_s_setprio(0);
    }

#pragma unroll
    for (int j = 0; j < NJ; ++j) {
        const int n = n0 + wn + j * 16 + lq;
        const float bv = bias[n];
#pragma unroll
        for (int i = 0; i < 4; ++i) {
#pragma unroll
            for (int r = 0; r < 4; ++r) {
                const int m = m0 + wm + i * 16 + hi * 4 + r;
                Out[(size_t)m * DM + n] = acc[i][j][r] + bv;
            }
        }
    }
}

// ---------------------------------------------------------------------------
extern "C" void kernel_launch(void* const* d_in, const int* in_sizes, int n_in,
                              void* d_out, int out_size, void* d_ws, size_t ws_size,
                              hipStream_t stream) {
    (void)in_sizes; (void)n_in; (void)out_size;
    const float* query = (const float*)d_in[0];
    const float* key_  = (const float*)d_in[1];
    const float* value = (const float*)d_in[2];
    const float* Wq = (const float*)d_in[3];
    const float* bq = (const float*)d_in[4];
    const float* Wk = (const float*)d_in[5];
    const float* bk = (const float*)d_in[6];
    const float* Wv = (const float*)d_in[7];
    const float* bv = (const float*)d_in[8];
    const float* Wo = (const float*)d_in[9];
    const float* bo = (const float*)d_in[10];

    char* ws = (char*)d_ws;
    const size_t WSZ = (size_t)512 * 1024;        // per transposed weight
    const size_t XSZ = (size_t)8 * 1024 * 1024;   // per [8192][512] bf16 buffer
    const float QSC = 0.125f * 1.4426950408889634f;  // 1/sqrt(dk) * log2(e)
    if (ws_size < 4 * WSZ + 7 * XSZ) return;

    __bf16* Wtq = (__bf16*)(ws);
    __bf16* Wtk = (__bf16*)(ws + WSZ);
    __bf16* Wtv = (__bf16*)(ws + 2 * WSZ);
    __bf16* Wto = (__bf16*)(ws + 3 * WSZ);
    char* xb = ws + 4 * WSZ;
    __bf16* Qb = (__bf16*)(xb);                 // -> P0 after projections
    __bf16* Kb = (__bf16*)(xb + XSZ);           // -> P1
    __bf16* Vb = (__bf16*)(xb + 2 * XSZ);       // -> MLM/MLL
    __bf16* Qp = (__bf16*)(xb + 3 * XSZ);
    __bf16* Kp = (__bf16*)(xb + 4 * XSZ);
    __bf16* Vt = (__bf16*)(xb + 5 * XSZ);       // written directly by V-proj GEMM
    __bf16* P0 = Qb;
    __bf16* P1 = Kb;
    float* MLM = (float*)Vb;
    float* MLL = MLM + 2 * 16 * SEQ;

    PrepArgs pa;
    pa.s[0] = query; pa.s[1] = key_; pa.s[2] = value;
    pa.d[0] = Qb; pa.d[1] = Kb; pa.d[2] = Vb;
    pa.W[0] = Wq; pa.W[1] = Wk; pa.W[2] = Wv; pa.W[3] = Wo;
    pa.Wt[0] = Wtq; pa.Wt[1] = Wtk; pa.Wt[2] = Wtv; pa.Wt[3] = Wto;
    prep_all<<<dim3(7168), 256, 0, stream>>>(pa);

    GemmArgs qa;
    qa.p[0] = {Qb, Wtq, bq, Qp, QSC, 0};
    qa.p[1] = {Kb, Wtk, bk, Kp, 1.0f, 0};
    qa.p[2] = {Vb, Wtv, bv, Vt, 1.0f, 1};       // V-proj writes Vt directly
    gemm_qkv<<<dim3(64, 4, 3), 256, 0, stream>>>(qa);

    flash_attn6<<<dim3(SEQ / 128, BATCH * HEADS, 2), 256, 0, stream>>>(
        Qp, Kp, Vt, P0, P1, MLM, MLL);

    gemm_out<<<dim3(64, 8), 256, 0, stream>>>(P0, P1, MLM, MLL, Wto, bo, (float*)d_out);
}